// Round 5
// baseline (548.181 us; speedup 1.0000x reference)
//
#include <hip/hip_runtime.h>

#define BS 4
#define SL 2048
#define NE 1024
#define NH 16
#define HD 64
#define N3 3072

typedef __attribute__((ext_vector_type(8))) __bf16 bf16x8;
typedef __attribute__((ext_vector_type(4))) float f32x4;
typedef unsigned short u16;

__device__ __forceinline__ u16 f2bf(float f) {
  union { float f; unsigned int u; } v; v.f = f;
  unsigned int r = v.u + 0x7FFFu + ((v.u >> 16) & 1u);
  return (u16)(r >> 16);
}
__device__ __forceinline__ u16 f2bf_rtz(float f) {
  union { float f; unsigned int u; } v; v.f = f;
  return (u16)(v.u >> 16);
}

// global -> LDS direct 16B copy. LDS dest is WAVE-UNIFORM base; HW adds
// lane*16. Global address is per-lane.
__device__ __forceinline__ void gld16(const void* g, void* l) {
#if __has_builtin(__builtin_amdgcn_global_load_lds)
  __builtin_amdgcn_global_load_lds(
      (const __attribute__((address_space(1))) unsigned int*)g,
      (__attribute__((address_space(3))) unsigned int*)l, 16, 0, 0);
#else
  *(int4*)((char*)l + (size_t)(threadIdx.x & 63) * 16) = *(const int4*)g;
#endif
}

// ---------------- x fp32 -> bf16 ----------------
__global__ void convert_x(const float* __restrict__ x, u16* __restrict__ xb) {
  int i = (blockIdx.x * 256 + threadIdx.x) * 8;
  float4 f0 = *(const float4*)(x + i);
  float4 f1 = *(const float4*)(x + i + 4);
  union { int4 v; u16 h[8]; } p;
  p.h[0] = f2bf(f0.x); p.h[1] = f2bf(f0.y);
  p.h[2] = f2bf(f0.z); p.h[3] = f2bf(f0.w);
  p.h[4] = f2bf(f1.x); p.h[5] = f2bf(f1.y);
  p.h[6] = f2bf(f1.z); p.h[7] = f2bf(f1.w);
  *(int4*)(xb + i) = p.v;
}

// ---------------- W transpose+convert: Wt[n*K+k] = bf16(W[k*N+n]) ----------
__global__ void transpose_w(const float* __restrict__ W, u16* __restrict__ Wt,
                            int K, int N) {
  __shared__ u16 tile[32][33];
  int bn = blockIdx.x * 32, bk = blockIdx.y * 32;
  int tx = threadIdx.x, ty = threadIdx.y;  // blockDim = (32, 8)
  for (int r = 0; r < 32; r += 8)
    tile[ty + r][tx] = f2bf(W[(size_t)(bk + ty + r) * N + bn + tx]);
  __syncthreads();
  for (int r = 0; r < 32; r += 8)
    Wt[(size_t)(bn + ty + r) * K + bk + tx] = tile[tx][ty + r];
}

// ---------------- GEMM: C[M,N] = A[M,K] @ Bt[N,K]^T + bias[N] ---------------
// A, Bt bf16 staged via global_load_lds width=16. C32: store fp32 else bf16.
template <int C32>
__global__ __launch_bounds__(256) void gemm_bt(
    const u16* __restrict__ A, const u16* __restrict__ Bt,
    const float* __restrict__ bias, void* __restrict__ C, int M, int N, int K,
    int lda) {
  __shared__ u16 As[128 * 32];
  __shared__ u16 Bs[128 * 32];

  const int tid = threadIdx.x;
  const int wave = tid >> 6, lane = tid & 63;
  const int lq = lane >> 4, lr = lane & 15;
  const int m0 = blockIdx.y * 128, n0 = blockIdx.x * 128;
  const int wm = (wave & 1) * 64, wn = (wave >> 1) * 64;

  const f32x4 fzero = {0.f, 0.f, 0.f, 0.f};
  f32x4 acc[4][4];
#pragma unroll
  for (int i = 0; i < 4; i++)
#pragma unroll
    for (int j = 0; j < 4; j++) acc[i][j] = fzero;

  for (int k0 = 0; k0 < K; k0 += 32) {
    __syncthreads();  // previous iteration's LDS readers are done
#pragma unroll
    for (int t = 0; t < 2; t++) {
      int chunk = wave * 2 + t;  // 1 KB chunk = 16 rows x 64 B
      const u16* ga = A + (size_t)(m0 + chunk * 16 + (lane >> 2)) * lda + k0 +
                      (lane & 3) * 8;
      gld16(ga, &As[chunk * 512]);
      const u16* gb = Bt + (size_t)(n0 + chunk * 16 + (lane >> 2)) * K + k0 +
                      (lane & 3) * 8;
      gld16(gb, &Bs[chunk * 512]);
    }
    __syncthreads();  // drains vmcnt (global_load_lds) + lgkm

    bf16x8 af[4], bfr[4];
#pragma unroll
    for (int i = 0; i < 4; i++)
      af[i] = *(const bf16x8*)&As[(wm + i * 16 + lr) * 32 + lq * 8];
#pragma unroll
    for (int j = 0; j < 4; j++)
      bfr[j] = *(const bf16x8*)&Bs[(wn + j * 16 + lr) * 32 + lq * 8];
#pragma unroll
    for (int i = 0; i < 4; i++)
#pragma unroll
      for (int j = 0; j < 4; j++)
        acc[i][j] = __builtin_amdgcn_mfma_f32_16x16x32_bf16(af[i], bfr[j],
                                                            acc[i][j], 0, 0, 0);
  }

  // Epilogue. C/D layout: col = lane&15, row = (lane>>4)*4 + reg.
#pragma unroll
  for (int j = 0; j < 4; j++) {
    int col = n0 + wn + j * 16 + lr;
    float bv = bias[col];
#pragma unroll
    for (int i = 0; i < 4; i++) {
#pragma unroll
      for (int r = 0; r < 4; r++) {
        int row = m0 + wm + i * 16 + lq * 4 + r;
        float val = acc[i][j][r] + bv;
        if (C32) ((float*)C)[(size_t)row * N + col] = val;
        else     ((u16*)C)[(size_t)row * N + col]   = f2bf(val);
      }
    }
  }
}

// ---------------- Flash attention (causal), paired q-tiles ----------------
// Block (bh, p) handles q-tiles {p, 31-p} of head bh&15, batch bh>>4 -> every
// block does exactly 33 tile-halves (perfect balance). All 16 p-blocks of one
// (b,h) share linear-id mod 8 -> same XCD -> K/V L2 reuse. K/V global loads
// are register double-buffered (prefetch kt+1 behind compute of kt).
#define KSTR 72  // 64 + 8 pad elems (rows 16B aligned)

#define MFMA16(a, b, c) __builtin_amdgcn_mfma_f32_16x16x32_bf16(a, b, c, 0, 0, 0)

// softmax update for one half: s (C-layout) -> P in Ps, updates m/l/o-scale
__device__ __forceinline__ void softmax_half(f32x4 (&s)[4], float (&m_)[4],
                                             float (&l_)[4], f32x4 (&o)[4],
                                             u16* __restrict__ myP, int lq,
                                             int lr) {
#pragma unroll
  for (int r = 0; r < 4; r++) {
    float mt = fmaxf(fmaxf(s[0][r], s[1][r]), fmaxf(s[2][r], s[3][r]));
#pragma unroll
    for (int off = 1; off < 16; off <<= 1)
      mt = fmaxf(mt, __shfl_xor(mt, off, 16));
    float mn = fmaxf(m_[r], mt);
    float alpha = __expf(m_[r] - mn);
    m_[r] = mn;
    float psum = 0.f;
#pragma unroll
    for (int j = 0; j < 4; j++) {
      float pv = __expf(s[j][r] - mn);
      s[j][r] = pv;
      psum += pv;
    }
    l_[r] = l_[r] * alpha + psum;  // per-lane partial; reduced in epilogue
#pragma unroll
    for (int j = 0; j < 4; j++) o[j][r] *= alpha;
  }
#pragma unroll
  for (int j = 0; j < 4; j++)
#pragma unroll
    for (int r = 0; r < 4; r++)
      myP[(lq * 4 + r) * KSTR + j * 16 + lr] = f2bf_rtz(s[j][r]);
}

__global__ __launch_bounds__(256, 4) void attn_paired(u16* __restrict__ qkv) {
  __shared__ u16 Ks[64 * KSTR];
  __shared__ u16 Vs[64 * KSTR];
  __shared__ u16 Ps[2][4][16 * KSTR];

  const int tid = threadIdx.x;
  const int w = tid >> 6, lane = tid & 63;
  const int lq = lane >> 4, lr = lane & 15;
  const int bh = blockIdx.x, p = blockIdx.y;
  const int h = bh & (NH - 1), b = bh >> 4;
  const int qt0 = p, qt1 = (SL / 64 - 1) - p;

  u16* base = qkv + (size_t)b * SL * N3;
  const u16* kbase = base + NE + h * HD;  // K plane; V plane at +NE

  // staging slots: this thread owns key=skey, d-chunks sd0 and sd0+32
  const int skey = tid & 63, sd0 = (tid >> 6) * 8;

  int4 preK[2][2], preV[2][2];
#define LOADT(buf, key0)                                                   \
  {                                                                        \
    const u16* kr = kbase + (size_t)((key0) + skey) * N3 + sd0;            \
    _Pragma("unroll") for (int t = 0; t < 2; t++) {                        \
      preK[buf][t] = *(const int4*)(kr + t * 32);                          \
      preV[buf][t] = *(const int4*)(kr + NE + t * 32);                     \
    }                                                                      \
  }
#define STORET(buf)                                                        \
  {                                                                        \
    _Pragma("unroll") for (int t = 0; t < 2; t++) {                        \
      *(int4*)&Ks[skey * KSTR + sd0 + t * 32] = preK[buf][t];              \
      union { int4 v; u16 u[8]; } tmp;                                     \
      tmp.v = preV[buf][t];                                                \
      _Pragma("unroll") for (int j = 0; j < 8; j++)                        \
          Vs[(sd0 + t * 32 + j) * KSTR + skey] = tmp.u[j];                 \
    }                                                                      \
  }

  bf16x8 qf[2][2];
#pragma unroll
  for (int half = 0; half < 2; half++) {
    int qt = half ? qt1 : qt0;
    const u16* qrow = base + (size_t)(qt * 64 + w * 16 + lr) * N3 + h * HD;
    qf[half][0] = *(const bf16x8*)(qrow + lq * 8);
    qf[half][1] = *(const bf16x8*)(qrow + 32 + lq * 8);
  }

  const f32x4 fzero = {0.f, 0.f, 0.f, 0.f};
  f32x4 o[2][4];
  float m_[2][4], l_[2][4];
#pragma unroll
  for (int half = 0; half < 2; half++)
#pragma unroll
    for (int r = 0; r < 4; r++) {
      o[half][r] = fzero;
      m_[half][r] = -1e30f;
      l_[half][r] = 0.f;
    }

  LOADT(0, 0);
  const int ktend = qt1 + 1;
  for (int kt = 0; kt < ktend; kt++) {
    __syncthreads();        // LDS consumers of tile kt-1 done
    STORET(kt & 1);
    if (kt + 1 < ktend) LOADT((kt + 1) & 1, (kt + 1) * 64);  // prefetch
    __syncthreads();

    if (kt <= qt0) {
      // ---- fused dual: K/V frags shared by both halves; lo diag iff kt==qt0
      f32x4 s[2][4];
#pragma unroll
      for (int j = 0; j < 4; j++) {
        bf16x8 kf0 = *(const bf16x8*)&Ks[(j * 16 + lr) * KSTR + lq * 8];
        bf16x8 kf1 = *(const bf16x8*)&Ks[(j * 16 + lr) * KSTR + 32 + lq * 8];
        f32x4 z1 = MFMA16(qf[1][0], kf0, fzero);
        f32x4 z0 = MFMA16(qf[0][0], kf0, fzero);
        s[1][j] = MFMA16(qf[1][1], kf1, z1);
        s[0][j] = MFMA16(qf[0][1], kf1, z0);
      }
#pragma unroll
      for (int half = 0; half < 2; half++)
#pragma unroll
        for (int j = 0; j < 4; j++)
#pragma unroll
          for (int r = 0; r < 4; r++) s[half][j][r] *= 0.125f;
      if (kt == qt0) {  // diagonal for lo half
#pragma unroll
        for (int j = 0; j < 4; j++)
#pragma unroll
          for (int r = 0; r < 4; r++)
            if (j * 16 + lr > w * 16 + lq * 4 + r) s[0][j][r] = -1e30f;
      }
      softmax_half(s[1], m_[1], l_[1], o[1], &Ps[1][w][0], lq, lr);
      softmax_half(s[0], m_[0], l_[0], o[0], &Ps[0][w][0], lq, lr);
      __asm__ volatile("s_waitcnt lgkmcnt(0)" ::: "memory");
      bf16x8 pf1a = *(const bf16x8*)&Ps[1][w][lr * KSTR + lq * 8];
      bf16x8 pf1b = *(const bf16x8*)&Ps[1][w][lr * KSTR + 32 + lq * 8];
      bf16x8 pf0a = *(const bf16x8*)&Ps[0][w][lr * KSTR + lq * 8];
      bf16x8 pf0b = *(const bf16x8*)&Ps[0][w][lr * KSTR + 32 + lq * 8];
#pragma unroll
      for (int jd = 0; jd < 4; jd++) {
        bf16x8 vf0 = *(const bf16x8*)&Vs[(jd * 16 + lr) * KSTR + lq * 8];
        bf16x8 vf1 = *(const bf16x8*)&Vs[(jd * 16 + lr) * KSTR + 32 + lq * 8];
        o[1][jd] = MFMA16(pf1a, vf0, o[1][jd]);
        o[0][jd] = MFMA16(pf0a, vf0, o[0][jd]);
        o[1][jd] = MFMA16(pf1b, vf1, o[1][jd]);
        o[0][jd] = MFMA16(pf0b, vf1, o[0][jd]);
      }
    } else {
      // ---- hi half only; diag iff kt == qt1
      f32x4 s[4];
#pragma unroll
      for (int j = 0; j < 4; j++) {
        bf16x8 kf0 = *(const bf16x8*)&Ks[(j * 16 + lr) * KSTR + lq * 8];
        bf16x8 kf1 = *(const bf16x8*)&Ks[(j * 16 + lr) * KSTR + 32 + lq * 8];
        f32x4 z = MFMA16(qf[1][0], kf0, fzero);
        s[j] = MFMA16(qf[1][1], kf1, z);
      }
#pragma unroll
      for (int j = 0; j < 4; j++)
#pragma unroll
        for (int r = 0; r < 4; r++) s[j][r] *= 0.125f;
      if (kt == qt1) {
#pragma unroll
        for (int j = 0; j < 4; j++)
#pragma unroll
          for (int r = 0; r < 4; r++)
            if (j * 16 + lr > w * 16 + lq * 4 + r) s[j][r] = -1e30f;
      }
      softmax_half(s, m_[1], l_[1], o[1], &Ps[1][w][0], lq, lr);
      __asm__ volatile("s_waitcnt lgkmcnt(0)" ::: "memory");
      bf16x8 pfa = *(const bf16x8*)&Ps[1][w][lr * KSTR + lq * 8];
      bf16x8 pfb = *(const bf16x8*)&Ps[1][w][lr * KSTR + 32 + lq * 8];
#pragma unroll
      for (int jd = 0; jd < 4; jd++) {
        bf16x8 vf0 = *(const bf16x8*)&Vs[(jd * 16 + lr) * KSTR + lq * 8];
        bf16x8 vf1 = *(const bf16x8*)&Vs[(jd * 16 + lr) * KSTR + 32 + lq * 8];
        o[1][jd] = MFMA16(pfa, vf0, o[1][jd]);
        o[1][jd] = MFMA16(pfb, vf1, o[1][jd]);
      }
    }
  }

  // epilogue: reduce per-lane l partials across the 16 col-lanes, write Y
  // over the Q slot (block-private rows -> in-place safe)
#pragma unroll
  for (int half = 0; half < 2; half++) {
    int qt = half ? qt1 : qt0;
#pragma unroll
    for (int r = 0; r < 4; r++) {
      float lsum = l_[half][r];
#pragma unroll
      for (int off = 1; off < 16; off <<= 1) lsum += __shfl_xor(lsum, off, 16);
      float inv = 1.0f / lsum;
      int srow = qt * 64 + w * 16 + lq * 4 + r;
      u16* yrow = base + (size_t)srow * N3 + h * HD;
#pragma unroll
      for (int j = 0; j < 4; j++) yrow[j * 16 + lr] = f2bf(o[half][j][r] * inv);
    }
  }
}

// ---------------- host launch ----------------
extern "C" void kernel_launch(void* const* d_in, const int* in_sizes, int n_in,
                              void* d_out, int out_size, void* d_ws,
                              size_t ws_size, hipStream_t stream) {
  // inputs (fp32 / int32): x, mask(ignored - analytic causal), Wqkv, bqkv,
  // Wo, bo
  const float* x    = (const float*)d_in[0];
  const float* Wqkv = (const float*)d_in[2];
  const float* bqkv = (const float*)d_in[3];
  const float* Wo   = (const float*)d_in[4];
  const float* bo   = (const float*)d_in[5];

  u16* WqkvT  = (u16*)d_ws;                       // [3072,1024] bf16
  u16* WoT    = WqkvT + (size_t)N3 * NE;          // [1024,1024] bf16
  u16* xb     = WoT + (size_t)NE * NE;            // [8192,1024] bf16
  u16* qkvbuf = xb + (size_t)BS * SL * NE;        // [8192,3072] bf16

  convert_x<<<(BS * SL * NE) / (256 * 8), 256, 0, stream>>>(x, xb);
  transpose_w<<<dim3(N3 / 32, NE / 32), dim3(32, 8), 0, stream>>>(Wqkv, WqkvT,
                                                                  NE, N3);
  transpose_w<<<dim3(NE / 32, NE / 32), dim3(32, 8), 0, stream>>>(Wo, WoT, NE,
                                                                  NE);
  gemm_bt<0><<<dim3(N3 / 128, (BS * SL) / 128), 256, 0, stream>>>(
      xb, WqkvT, bqkv, qkvbuf, BS * SL, N3, NE, NE);
  attn_paired<<<dim3(BS * NH, SL / 128), 256, 0, stream>>>(qkvbuf);
  gemm_bt<1><<<dim3(NE / 128, (BS * SL) / 128), 256, 0, stream>>>(
      qkvbuf, WoT, bo, d_out, BS * SL, NE, NE, N3);
}